// Round 17
// baseline (704.964 us; speedup 1.0000x reference)
//
#include <hip/hip_runtime.h>
#include <stdint.h>

// GraphConvLayer: out[n,:] = W[type[n]] @ (A @ x)[n,:]
// N=16384, D=128, T=8.  A is 1 GiB f32 read exactly once -> HBM floor ~163us.
// Round 17: ZERO-BARRIER self-paced waves.
//  - A is wave-PRIVATE: each wave DMAs its own 16 rows (8x1KB calls/tile)
//    into its own 2x8KB LDS buffers; producer == consumer == same wave, so
//    correctness needs only that wave's vmcnt. No s_barrier in the K loop.
//  - X fragments are register-resident via pinned asm global_load_dwordx4
//    (volatile -> RA can't sink; coalesced 4 lanes / 64B segment), double
//    parity, issued ONE PHASE AHEAD and immediately before the A-DMA batch:
//    the per-phase s_waitcnt vmcnt(24) (16 X + 8 A just issued) then lands
//    exactly on X_t and A_t - the vmcnt FIFO that killed R16 now works FOR us.
//  - sched_barrier(0) after each wait (rule #18: MFMA hoists past asm waits).
// Phase cost -> max(HBM 3300cy, LDS 1500cy, MFMA 160cy) instead of the sum.

#define N_NODES 16384
#define DIM     128
#define NTYPES  8
#define BM      64
#define BK      128
#define NT_K    (N_NODES / BK)   // 128 tiles

typedef float  f32x4  __attribute__((ext_vector_type(4)));
typedef __bf16 bf16x8 __attribute__((ext_vector_type(8)));

__device__ __attribute__((aligned(16))) unsigned short g_xT[DIM * N_NODES];      // [d][n], 4 MiB bf16
__device__ __attribute__((aligned(16))) unsigned short g_Wb[NTYPES * DIM * DIM]; // [t][o][d], 256 KiB

__device__ __forceinline__ unsigned int f2b(float f) {
    unsigned int u = __float_as_uint(f);
    u += 0x7FFFu + ((u >> 16) & 1u);   // round-to-nearest-even
    return u >> 16;
}
#define BF_LO(u) __uint_as_float((unsigned int)(u) << 16)
#define BF_HI(u) __uint_as_float((unsigned int)(u) & 0xFFFF0000u)

__device__ __forceinline__ bf16x8 cvt8(const f32x4 lo, const f32x4 hi) {
    bf16x8 r;
    r[0] = (__bf16)lo[0]; r[1] = (__bf16)lo[1]; r[2] = (__bf16)lo[2]; r[3] = (__bf16)lo[3];
    r[4] = (__bf16)hi[0]; r[5] = (__bf16)hi[1]; r[6] = (__bf16)hi[2]; r[7] = (__bf16)hi[3];
    return r;
}

// ---------------- fused prep kernel ----------------

__global__ void prep_all(const float* __restrict__ x, const float* __restrict__ w) {
    const int tid = threadIdx.x;
    if (blockIdx.x < 64) {
        int n = blockIdx.x * 256 + tid;
        const float* row = x + (size_t)n * DIM;
#pragma unroll
        for (int d0 = 0; d0 < DIM; d0 += 4) {
            float4 v = *(const float4*)(row + d0);
            g_xT[(d0 + 0) * N_NODES + n] = (unsigned short)f2b(v.x);
            g_xT[(d0 + 1) * N_NODES + n] = (unsigned short)f2b(v.y);
            g_xT[(d0 + 2) * N_NODES + n] = (unsigned short)f2b(v.z);
            g_xT[(d0 + 3) * N_NODES + n] = (unsigned short)f2b(v.w);
        }
    } else {
        int base = ((blockIdx.x - 64) * 256 + tid) * 16;
#pragma unroll
        for (int j = 0; j < 4; ++j) {
            float4 v = *(const float4*)(w + base + j * 4);
            ushort4 o;
            o.x = (unsigned short)f2b(v.x); o.y = (unsigned short)f2b(v.y);
            o.z = (unsigned short)f2b(v.z); o.w = (unsigned short)f2b(v.w);
            *(ushort4*)(g_Wb + base + j * 4) = o;
        }
    }
}

// ---------------- main fused kernel ----------------

#define GLOAD16(g, l) __builtin_amdgcn_global_load_lds(                         \
    (const __attribute__((address_space(1))) unsigned int*)(g),                 \
    (__attribute__((address_space(3))) unsigned int*)(l), 16, 0, 0)

// pinned X load (volatile asm: ordered, can't be sunk); dwordx4 = bf16x8
#define XLOAD(reg, ptr, off) \
    asm volatile("global_load_dwordx4 %0, %1, off offset:" #off : "=v"(reg) : "v"(ptr))

// 16 X loads for the NEXT tile: frag (nt, kc), kc imm offset = kc*64B
#define ISSUE_X(P) do {                                              \
    XLOAD(P##00, bx0,   0); XLOAD(P##01, bx1,   0);                  \
    XLOAD(P##02, bx2,   0); XLOAD(P##03, bx3,   0);                  \
    XLOAD(P##10, bx0,  64); XLOAD(P##11, bx1,  64);                  \
    XLOAD(P##12, bx2,  64); XLOAD(P##13, bx3,  64);                  \
    XLOAD(P##20, bx0, 128); XLOAD(P##21, bx1, 128);                  \
    XLOAD(P##22, bx2, 128); XLOAD(P##23, bx3, 128);                  \
    XLOAD(P##30, bx0, 192); XLOAD(P##31, bx1, 192);                  \
    XLOAD(P##32, bx2, 192); XLOAD(P##33, bx3, 192);                  \
    bx0 += BK; bx1 += BK; bx2 += BK; bx3 += BK;                      \
} while (0)

// 8 private A-DMA calls for the NEXT tile: call j = rows 2j,2j+1 of this
// wave's 16-row m-tile (1KB linear dest in the wave's private buffer)
#define ISSUE_A(Abase) do {                                          \
    GLOAD16(pA0, (Abase) + 0 * 1024);  GLOAD16(pA1, (Abase) + 1 * 1024);  \
    GLOAD16(pA2, (Abase) + 2 * 1024);  GLOAD16(pA3, (Abase) + 3 * 1024);  \
    GLOAD16(pA4, (Abase) + 4 * 1024);  GLOAD16(pA5, (Abase) + 5 * 1024);  \
    GLOAD16(pA6, (Abase) + 6 * 1024);  GLOAD16(pA7, (Abase) + 7 * 1024);  \
    pA0 += BK; pA1 += BK; pA2 += BK; pA3 += BK;                      \
    pA4 += BK; pA5 += BK; pA6 += BK; pA7 += BK;                      \
} while (0)

// one k-substep: A frag from private LDS (2 f32x4 + cvt) x 4 register X frags
#define KSUB(Ab, kc, X0_, X1_, X2_, X3_) do {                                   \
    f32x4 _e = *(const f32x4*)((Ab) + aoE + (kc) * 128);                        \
    f32x4 _o = *(const f32x4*)((Ab) + aoO + (kc) * 128);                        \
    bf16x8 _a = cvt8(_e, _o);                                                   \
    acc0 = __builtin_amdgcn_mfma_f32_16x16x32_bf16(_a, X0_, acc0, 0, 0, 0);     \
    acc1 = __builtin_amdgcn_mfma_f32_16x16x32_bf16(_a, X1_, acc1, 0, 0, 0);     \
    acc2 = __builtin_amdgcn_mfma_f32_16x16x32_bf16(_a, X2_, acc2, 0, 0, 0);     \
    acc3 = __builtin_amdgcn_mfma_f32_16x16x32_bf16(_a, X3_, acc3, 0, 0, 0);     \
} while (0)

#define COMPUTE(P, Ab) do {                                  \
    KSUB(Ab, 0, P##00, P##01, P##02, P##03);                 \
    KSUB(Ab, 1, P##10, P##11, P##12, P##13);                 \
    KSUB(Ab, 2, P##20, P##21, P##22, P##23);                 \
    KSUB(Ab, 3, P##30, P##31, P##32, P##33);                 \
} while (0)

#define WAITV(N) do {                                        \
    asm volatile("s_waitcnt vmcnt(" #N ")" ::: "memory");    \
    __builtin_amdgcn_sched_barrier(0);                       \
} while (0)

__global__ __launch_bounds__(512, 1) void gconv_main(
    const float* __restrict__ adj,
    const int* __restrict__ types,
    float* __restrict__ out)
{
    __shared__ __align__(16) unsigned char lds[8 * 16384];   // 128 KiB: per-wave 2x8KB A bufs (agg reuse)

    const int tid  = threadIdx.x;
    const int w    = tid >> 6;          // 0..7
    const int l    = tid & 63;
    const int m0   = blockIdx.x * BM;

    const int mrow = (w & 3) * 16;      // wave's 16 output rows (of 64)
    const int ncol = (w >> 2) * 64;     // wave's 64 output cols (of 128)

    unsigned char* AbA = lds + w * 16384;          // private buffer, even tiles
    unsigned char* AbB = AbA + 8192;               // odd tiles

    f32x4 acc0 = {}, acc1 = {}, acc2 = {}, acc3 = {};

    // ---- private A-DMA source pointers (pre-swizzled; linear dest, m173) ----
    // call j: row = mrow + 2j + (l>>5); phys chunk l&31 <- src chunk (l&31)^(row&7)
    const int r0 = (l >> 5);
    const float* pA0 = adj + (size_t)(m0 + mrow +  0 + r0) * N_NODES + (((l & 31) ^ ((mrow +  0 + r0) & 7)) << 2);
    const float* pA1 = adj + (size_t)(m0 + mrow +  2 + r0) * N_NODES + (((l & 31) ^ ((mrow +  2 + r0) & 7)) << 2);
    const float* pA2 = adj + (size_t)(m0 + mrow +  4 + r0) * N_NODES + (((l & 31) ^ ((mrow +  4 + r0) & 7)) << 2);
    const float* pA3 = adj + (size_t)(m0 + mrow +  6 + r0) * N_NODES + (((l & 31) ^ ((mrow +  6 + r0) & 7)) << 2);
    const float* pA4 = adj + (size_t)(m0 + mrow +  8 + r0) * N_NODES + (((l & 31) ^ ((mrow +  8 + r0) & 7)) << 2);
    const float* pA5 = adj + (size_t)(m0 + mrow + 10 + r0) * N_NODES + (((l & 31) ^ ((mrow + 10 + r0) & 7)) << 2);
    const float* pA6 = adj + (size_t)(m0 + mrow + 12 + r0) * N_NODES + (((l & 31) ^ ((mrow + 12 + r0) & 7)) << 2);
    const float* pA7 = adj + (size_t)(m0 + mrow + 14 + r0) * N_NODES + (((l & 31) ^ ((mrow + 14 + r0) & 7)) << 2);

    // ---- A read offsets within private buf: row r = l&15 (512B rows),
    // ksub kc reads phys chunks (kc*8+2h)^(l&7), +1  (h = l>>4) ----
    const int h   = l >> 4;
    const int aoE = (l & 15) * 512 + (((2 * h)     ^ (l & 7)) << 4);
    const int aoO = (l & 15) * 512 + (((2 * h + 1) ^ (l & 7)) << 4);

    // ---- X pointers: frag nt at g_xT row ncol+nt*16+(l&15), k-granule h*8;
    // 4 lanes (same l&15) cover one 64B segment. Advance BK shorts/phase. ----
    const unsigned short* bx0 = g_xT + (size_t)(ncol +  0 + (l & 15)) * N_NODES + h * 8;
    const unsigned short* bx1 = g_xT + (size_t)(ncol + 16 + (l & 15)) * N_NODES + h * 8;
    const unsigned short* bx2 = g_xT + (size_t)(ncol + 32 + (l & 15)) * N_NODES + h * 8;
    const unsigned short* bx3 = g_xT + (size_t)(ncol + 48 + (l & 15)) * N_NODES + h * 8;

    // ---- X register parities (asm outputs; named, never arrays) ----
    bf16x8 p00, p01, p02, p03, p10, p11, p12, p13,
           p20, p21, p22, p23, p30, p31, p32, p33;
    bf16x8 q00, q01, q02, q03, q10, q11, q12, q13,
           q20, q21, q22, q23, q30, q31, q32, q33;

    // ---- prologue: tile 0 -> p / AbA (24 VMEM ops in flight) ----
    ISSUE_X(p);
    ISSUE_A(AbA);

    // ---- 126 phases in the loop + 2 tail; NO BARRIERS ----
    for (int i = 0; i < 63; ++i) {
        // t = 2i (even): issue tile t+1 -> q/AbB, wait X_t+A_t, compute
        ISSUE_X(q); ISSUE_A(AbB);
        WAITV(24);
        COMPUTE(p, AbA);
        // t = 2i+1 (odd)
        ISSUE_X(p); ISSUE_A(AbA);
        WAITV(24);
        COMPUTE(q, AbB);
    }
    // t = 126: issue tile 127 -> q/AbB
    ISSUE_X(q); ISSUE_A(AbB);
    WAITV(24);
    COMPUTE(p, AbA);
    // t = 127
    WAITV(0);
    COMPUTE(q, AbB);
    __syncthreads();                    // rejoin waves before reusing LDS as agg

    // ---- epilogue: acc -> LDS agg (f32), then per-row W[type] dots ----
    float* agg = (float*)lds;   // [64][132] = 33792 B
#pragma unroll
    for (int rr = 0; rr < 4; ++rr) {
        const int gr = (mrow + h * 4 + rr) * 132 + ncol + (l & 15);
        agg[gr +  0] = acc0[rr];
        agg[gr + 16] = acc1[rr];
        agg[gr + 32] = acc2[rr];
        agg[gr + 48] = acc3[rr];
    }
    __syncthreads();

    const int rbase = w * 8;   // 8 rows per wave
    for (int rr = 0; rr < 8; ++rr) {
        const int rw = rbase + rr;
        const int nn = m0 + rw;
        const int ty = types[nn];                      // wave-uniform
        const unsigned short* Wt = g_Wb + ty * (DIM * DIM);
        const int o0 = l * 2;
        const float* aggRow = agg + rw * 132;
        float s0 = 0.f, s1 = 0.f;
#pragma unroll
        for (int d0 = 0; d0 < DIM; d0 += 8) {
            float4 ga = *(const float4*)(aggRow + d0);
            float4 gb = *(const float4*)(aggRow + d0 + 4);
            uint4 wa = *(const uint4*)(Wt + o0 * DIM + d0);
            uint4 wb = *(const uint4*)(Wt + (o0 + 1) * DIM + d0);
            s0 += ga.x * BF_LO(wa.x) + ga.y * BF_HI(wa.x) + ga.z * BF_LO(wa.y) + ga.w * BF_HI(wa.y);
            s0 += gb.x * BF_LO(wa.z) + gb.y * BF_HI(wa.z) + gb.z * BF_LO(wa.w) + gb.w * BF_HI(wa.w);
            s1 += ga.x * BF_LO(wb.x) + ga.y * BF_HI(wb.x) + ga.z * BF_LO(wb.y) + ga.w * BF_HI(wb.y);
            s1 += gb.x * BF_LO(wb.z) + gb.y * BF_HI(wb.z) + gb.z * BF_LO(wb.w) + gb.w * BF_HI(wb.w);
        }
        float2 res; res.x = s0; res.y = s1;
        *(float2*)(out + (size_t)nn * DIM + o0) = res;
    }
}

// ---------------- launch ----------------

extern "C" void kernel_launch(void* const* d_in, const int* in_sizes, int n_in,
                              void* d_out, int out_size, void* d_ws, size_t ws_size,
                              hipStream_t stream) {
    const float* x     = (const float*)d_in[0];
    const int*   types = (const int*)d_in[1];
    const float* adj   = (const float*)d_in[2];
    const float* wt    = (const float*)d_in[3];
    float* out = (float*)d_out;

    hipLaunchKernelGGL(prep_all, dim3(96), dim3(256), 0, stream, x, wt);
    hipLaunchKernelGGL(gconv_main, dim3(N_NODES / BM), dim3(512), 0, stream, adj, types, out);
}

// Round 18
// 302.489 us; speedup vs baseline: 2.3305x; 2.3305x over previous
//
#include <hip/hip_runtime.h>
#include <stdint.h>

// GraphConvLayer: out[n,:] = W[type[n]] @ (A @ x)[n,:]
// N=16384, D=128, T=8.  A is 1 GiB f32 read exactly once -> HBM floor ~163us.
// Round 18: make per-CU LDS time (was 165us ~= HBM floor -> serialized 2x)
// strictly smaller than HBM time, then hide it under one barrier/phase:
//  - A stored in LDS as BF16 (reg-staged: pinned asm loads -> cvt -> swizzled
//    ds_write_b64), halving A LDS bytes. 2 x 16KB buffers.
//  - Wave config 2m x 4n (wave tile 32x32): X read redundancy 4x -> 2x.
//  - X: R13's verified DMA path, but THREE 32KB buffers -> XD(t+2) lands in
//    the buffer consumed at t-1 (already barrier-protected) -> the post-
//    compute barrier disappears. ONE barrier per phase.
//  - vmcnt FIFO audited: steady top-of-phase = vmcnt(8) lgkmcnt(0);
//    store-side WAITV(4); never a full drain until the tail.
// New LDS total ~18MB/block (~95us/CU) < HBM 163us -> overlap target ~200us.

#define N_NODES 16384
#define DIM     128
#define NTYPES  8
#define BM      64
#define BK      128
#define NT_K    (N_NODES / BK)   // 128 phases

typedef float  f32x4  __attribute__((ext_vector_type(4)));
typedef __bf16 bf16x4 __attribute__((ext_vector_type(4)));
typedef __bf16 bf16x8 __attribute__((ext_vector_type(8)));

__device__ __attribute__((aligned(16))) unsigned short g_xT[DIM * N_NODES];      // [d][n], 4 MiB bf16
__device__ __attribute__((aligned(16))) unsigned short g_Wb[NTYPES * DIM * DIM]; // [t][o][d], 256 KiB

__device__ __forceinline__ unsigned int f2b(float f) {
    unsigned int u = __float_as_uint(f);
    u += 0x7FFFu + ((u >> 16) & 1u);   // round-to-nearest-even
    return u >> 16;
}
#define BF_LO(u) __uint_as_float((unsigned int)(u) << 16)
#define BF_HI(u) __uint_as_float((unsigned int)(u) & 0xFFFF0000u)

__device__ __forceinline__ bf16x4 cvt4(const f32x4 v) {
    bf16x4 r;
    r[0] = (__bf16)v[0]; r[1] = (__bf16)v[1]; r[2] = (__bf16)v[2]; r[3] = (__bf16)v[3];
    return r;
}

// ---------------- fused prep kernel ----------------

__global__ void prep_all(const float* __restrict__ x, const float* __restrict__ w) {
    const int tid = threadIdx.x;
    if (blockIdx.x < 64) {
        int n = blockIdx.x * 256 + tid;
        const float* row = x + (size_t)n * DIM;
#pragma unroll
        for (int d0 = 0; d0 < DIM; d0 += 4) {
            float4 v = *(const float4*)(row + d0);
            g_xT[(d0 + 0) * N_NODES + n] = (unsigned short)f2b(v.x);
            g_xT[(d0 + 1) * N_NODES + n] = (unsigned short)f2b(v.y);
            g_xT[(d0 + 2) * N_NODES + n] = (unsigned short)f2b(v.z);
            g_xT[(d0 + 3) * N_NODES + n] = (unsigned short)f2b(v.w);
        }
    } else {
        int base = ((blockIdx.x - 64) * 256 + tid) * 16;
#pragma unroll
        for (int j = 0; j < 4; ++j) {
            float4 v = *(const float4*)(w + base + j * 4);
            ushort4 o;
            o.x = (unsigned short)f2b(v.x); o.y = (unsigned short)f2b(v.y);
            o.z = (unsigned short)f2b(v.z); o.w = (unsigned short)f2b(v.w);
            *(ushort4*)(g_Wb + base + j * 4) = o;
        }
    }
}

// ---------------- main fused kernel ----------------

#define AB_BYTES 16384   // A tile bf16: 64 rows x 256B
#define XB_BYTES 32768   // X tile bf16: 128 d-rows x 256B

#define GLOAD16(g, l) __builtin_amdgcn_global_load_lds(                         \
    (const __attribute__((address_space(1))) unsigned int*)(g),                 \
    (__attribute__((address_space(3))) unsigned int*)(l), 16, 0, 0)

// pinned, fully-coalesced A load: instr j = 2 rows x 512B contiguous
#define ALOADI(reg, ptr) \
    asm volatile("global_load_dwordx4 %0, %1, off" : "=v"(reg) : "v"(ptr))

#define ISSUE_AL(R0, R1, R2, R3) do {            \
    ALOADI(R0, pA0); ALOADI(R1, pA1);            \
    ALOADI(R2, pA2); ALOADI(R3, pA3);            \
    pA0 += BK; pA1 += BK; pA2 += BK; pA3 += BK;  \
} while (0)

#define ISSUE_XD(Xb) do {                        \
    GLOAD16(gX0, (Xb) + 0 * 8192 + wq);          \
    GLOAD16(gX1, (Xb) + 1 * 8192 + wq);          \
    GLOAD16(gX2, (Xb) + 2 * 8192 + wq);          \
    GLOAD16(gX3, (Xb) + 3 * 8192 + wq);          \
    gX0 += BK; gX1 += BK; gX2 += BK; gX3 += BK;  \
} while (0)

// cvt + swizzled bf16 store of one staged tile (4 x 8B writes/thread)
#define STOREA(As, R0, R1, R2, R3) do {          \
    *(bf16x4*)((As) + aw0) = cvt4(R0);           \
    *(bf16x4*)((As) + aw1) = cvt4(R1);           \
    *(bf16x4*)((As) + aw2) = cvt4(R2);           \
    *(bf16x4*)((As) + aw3) = cvt4(R3);           \
} while (0)

// one k-substep (k=32): 2 A frags x 2 X frags -> 4 MFMA (A and X share `off`)
#define KS(Ab, Xb, off) do {                                                    \
    bf16x8 a0_ = *(const bf16x8*)((Ab) + arA0 + (off));                         \
    bf16x8 a1_ = *(const bf16x8*)((Ab) + arA1 + (off));                         \
    bf16x8 b0_ = *(const bf16x8*)((Xb) + xB0 + (off));                          \
    bf16x8 b1_ = *(const bf16x8*)((Xb) + xB1 + (off));                          \
    acc00 = __builtin_amdgcn_mfma_f32_16x16x32_bf16(a0_, b0_, acc00, 0, 0, 0);  \
    acc01 = __builtin_amdgcn_mfma_f32_16x16x32_bf16(a0_, b1_, acc01, 0, 0, 0);  \
    acc10 = __builtin_amdgcn_mfma_f32_16x16x32_bf16(a1_, b0_, acc10, 0, 0, 0);  \
    acc11 = __builtin_amdgcn_mfma_f32_16x16x32_bf16(a1_, b1_, acc11, 0, 0, 0);  \
} while (0)

#define COMPUTE(Ab, Xb) do {      \
    KS(Ab, Xb, off0);             \
    KS(Ab, Xb, off1);             \
    KS(Ab, Xb, off2);             \
    KS(Ab, Xb, off3);             \
} while (0)

#define WAITV(N) do {                                        \
    asm volatile("s_waitcnt vmcnt(" #N ")" ::: "memory");    \
    __builtin_amdgcn_sched_barrier(0);                       \
} while (0)

// phase top: tile t's X done (8 younger ops stay in flight), A stores visible
#define TOP(VM) do {                                                            \
    asm volatile("s_waitcnt vmcnt(" #VM ") lgkmcnt(0)\n\ts_barrier" ::: "memory"); \
    __builtin_amdgcn_sched_barrier(0);                                          \
} while (0)

// full steady phase: compute tile t; store A(t+1); issue AL(t+2), XD(t+2)
#define PHASE(Ac, Xc, As, S0,S1,S2,S3, L0,L1,L2,L3, Xi) do {  \
    TOP(8);                                                   \
    COMPUTE(Ac, Xc);                                          \
    __builtin_amdgcn_sched_barrier(0);                        \
    WAITV(4);                                                 \
    STOREA(As, S0, S1, S2, S3);                               \
    ISSUE_AL(L0, L1, L2, L3);                                 \
    ISSUE_XD(Xi);                                             \
} while (0)

__global__ __launch_bounds__(512, 1) void gconv_main(
    const float* __restrict__ adj,
    const int* __restrict__ types,
    float* __restrict__ out)
{
    __shared__ __align__(16) unsigned char lds[3 * XB_BYTES + 2 * AB_BYTES]; // 131072 B
    unsigned char* X0 = lds;
    unsigned char* X1 = lds + XB_BYTES;
    unsigned char* X2 = lds + 2 * XB_BYTES;
    unsigned char* Ab0 = lds + 3 * XB_BYTES;
    unsigned char* Ab1 = Ab0 + AB_BYTES;

    const int tid  = threadIdx.x;
    const int w    = tid >> 6;          // 0..7
    const int l    = tid & 63;
    const int m0   = blockIdx.x * BM;

    const int mrow = (w & 1) * 32;      // wave tile: 32 rows (2 m-tiles)
    const int ncol = (w >> 1) * 32;     //          x 32 cols (2 n-tiles)
    const int h    = l >> 4;            // k-quarter within ksub

    f32x4 acc00 = {}, acc01 = {}, acc10 = {}, acc11 = {};

    // ---- A staging: asm instr j = rows w*8 + j*2 + (l>>5), bytes (l&31)*16 ----
    const int rj0 = w * 8 + 0 + (l >> 5);
    const int rj1 = w * 8 + 2 + (l >> 5);
    const int rj2 = w * 8 + 4 + (l >> 5);
    const int rj3 = w * 8 + 6 + (l >> 5);
    const float* pA0 = adj + (size_t)(m0 + rj0) * N_NODES + (l & 31) * 4;
    const float* pA1 = adj + (size_t)(m0 + rj1) * N_NODES + (l & 31) * 4;
    const float* pA2 = adj + (size_t)(m0 + rj2) * N_NODES + (l & 31) * 4;
    const float* pA3 = adj + (size_t)(m0 + rj3) * N_NODES + (l & 31) * 4;
    // bf16 store addr: granule g=l&31 -> chunk g>>1 (XOR row&7), half g&1
    const int g_   = l & 31;
    const int aw0 = rj0 * 256 + ((((g_ >> 1) ^ (rj0 & 7))) << 4) + ((g_ & 1) << 3);
    const int aw1 = rj1 * 256 + ((((g_ >> 1) ^ (rj1 & 7))) << 4) + ((g_ & 1) << 3);
    const int aw2 = rj2 * 256 + ((((g_ >> 1) ^ (rj2 & 7))) << 4) + ((g_ & 1) << 3);
    const int aw3 = rj3 * 256 + ((((g_ >> 1) ^ (rj3 & 7))) << 4) + ((g_ & 1) << 3);

    // ---- X DMA (R13-verified): call j: d-row = j*32 + 4w + (l>>4) ----
    const int xdw = 4 * w + (l >> 4);
    const unsigned short* gX0 = g_xT + (size_t)( 0 + xdw) * N_NODES + (((l & 15) ^ (xdw & 7)) << 3);
    const unsigned short* gX1 = g_xT + (size_t)(32 + xdw) * N_NODES + (((l & 15) ^ (xdw & 7)) << 3);
    const unsigned short* gX2 = g_xT + (size_t)(64 + xdw) * N_NODES + (((l & 15) ^ (xdw & 7)) << 3);
    const unsigned short* gX3 = g_xT + (size_t)(96 + xdw) * N_NODES + (((l & 15) ^ (xdw & 7)) << 3);
    const int wq = w << 10;

    // ---- compute-side bases/offsets (A and X share the XOR-chunk formula) ----
    const int arA0 = (mrow +  0 + (l & 15)) * 256;
    const int arA1 = (mrow + 16 + (l & 15)) * 256;
    const int xB0  = (ncol +  0 + (l & 15)) * 256;
    const int xB1  = (ncol + 16 + (l & 15)) * 256;
    const int off0 = (( 0 + h) ^ (l & 7)) << 4;
    const int off1 = (( 4 + h) ^ (l & 7)) << 4;
    const int off2 = (( 8 + h) ^ (l & 7)) << 4;
    const int off3 = ((12 + h) ^ (l & 7)) << 4;

    // ---- A register parities (asm outputs, named) ----
    f32x4 p0, p1, p2, p3, q0, q1, q2, q3;

    // ---- prologue: AL(0)->p, XD(0), AL(1)->q, XD(1); store A(0) ----
    ISSUE_AL(p0, p1, p2, p3);     // tile 0
    ISSUE_XD(X0);
    ISSUE_AL(q0, q1, q2, q3);     // tile 1
    ISSUE_XD(X1);
    WAITV(12);                    // AL(0) done (XD0+AL1+XD1 = 12 in flight)
    STOREA(Ab0, p0, p1, p2, p3);

    // ---- 126 phases (21 x 6) + 2 tail ----
    for (int i = 0; i < 21; ++i) {
        PHASE(Ab0, X0, Ab1, q0,q1,q2,q3, p0,p1,p2,p3, X2);   // t%6=0
        PHASE(Ab1, X1, Ab0, p0,p1,p2,p3, q0,q1,q2,q3, X0);   // t%6=1
        PHASE(Ab0, X2, Ab1, q0,q1,q2,q3, p0,p1,p2,p3, X1);   // t%6=2
        PHASE(Ab1, X0, Ab0, p0,p1,p2,p3, q0,q1,q2,q3, X2);   // t%6=3
        PHASE(Ab0, X1, Ab1, q0,q1,q2,q3, p0,p1,p2,p3, X0);   // t%6=4
        PHASE(Ab1, X2, Ab0, p0,p1,p2,p3, q0,q1,q2,q3, X1);   // t%6=5
    }
    // t=126: compute; store A(127) (XD(127) stays in flight until next top)
    TOP(8);
    COMPUTE(Ab0, X0);
    __builtin_amdgcn_sched_barrier(0);
    WAITV(4);
    STOREA(Ab1, q0, q1, q2, q3);
    // t=127
    TOP(0);
    COMPUTE(Ab1, X1);
    __syncthreads();                    // drain before reusing LDS as agg

    // ---- epilogue: acc -> LDS agg (f32), then per-row W[type] dots ----
    float* agg = (float*)lds;   // [64][132] = 33792 B
#pragma unroll
    for (int r = 0; r < 4; ++r) {
        const int r0 = (mrow +  0 + h * 4 + r) * 132 + ncol + (l & 15);
        const int r1 = (mrow + 16 + h * 4 + r) * 132 + ncol + (l & 15);
        agg[r0 +  0] = acc00[r];
        agg[r0 + 16] = acc01[r];
        agg[r1 +  0] = acc10[r];
        agg[r1 + 16] = acc11[r];
    }
    __syncthreads();

    const int rbase = w * 8;   // 8 rows per wave
    for (int rr = 0; rr < 8; ++rr) {
        const int rw = rbase + rr;
        const int nn = m0 + rw;
        const int ty = types[nn];                      // wave-uniform
        const unsigned short* Wt = g_Wb + ty * (DIM * DIM);
        const int o0 = l * 2;
        const float* aggRow = agg + rw * 132;
        float s0 = 0.f, s1 = 0.f;
#pragma unroll
        for (int d0 = 0; d0 < DIM; d0 += 8) {
            float4 ga = *(const float4*)(aggRow + d0);
            float4 gb = *(const float4*)(aggRow + d0 + 4);
            uint4 wa = *(const uint4*)(Wt + o0 * DIM + d0);
            uint4 wb = *(const uint4*)(Wt + (o0 + 1) * DIM + d0);
            s0 += ga.x * BF_LO(wa.x) + ga.y * BF_HI(wa.x) + ga.z * BF_LO(wa.y) + ga.w * BF_HI(wa.y);
            s0 += gb.x * BF_LO(wa.z) + gb.y * BF_HI(wa.z) + gb.z * BF_LO(wa.w) + gb.w * BF_HI(wa.w);
            s1 += ga.x * BF_LO(wb.x) + ga.y * BF_HI(wb.x) + ga.z * BF_LO(wb.y) + ga.w * BF_HI(wb.y);
            s1 += gb.x * BF_LO(wb.z) + gb.y * BF_HI(wb.z) + gb.z * BF_LO(wb.w) + gb.w * BF_HI(wb.w);
        }
        float2 res; res.x = s0; res.y = s1;
        *(float2*)(out + (size_t)nn * DIM + o0) = res;
    }
}

// ---------------- launch ----------------

extern "C" void kernel_launch(void* const* d_in, const int* in_sizes, int n_in,
                              void* d_out, int out_size, void* d_ws, size_t ws_size,
                              hipStream_t stream) {
    const float* x     = (const float*)d_in[0];
    const int*   types = (const int*)d_in[1];
    const float* adj   = (const float*)d_in[2];
    const float* wt    = (const float*)d_in[3];
    float* out = (float*)d_out;

    hipLaunchKernelGGL(prep_all, dim3(96), dim3(256), 0, stream, x, wt);
    hipLaunchKernelGGL(gconv_main, dim3(N_NODES / BM), dim3(512), 0, stream, adj, types, out);
}

// Round 19
// 289.471 us; speedup vs baseline: 2.4354x; 1.0450x over previous
//
#include <hip/hip_runtime.h>
#include <stdint.h>

// GraphConvLayer: out[n,:] = W[type[n]] @ (A @ x)[n,:]
// N=16384, D=128, T=8.  A is 1 GiB f32 read exactly once -> HBM floor ~163us.
// Round 19 = Round 18 (best, 302us) + PAIRED A-issue for 1KB DRAM bursts.
// Theory: 16384 concurrent row-streams x 512B/page-visit exceed the DRAM
// activate-rate budget (~60% read efficiency). Issuing A tiles t+2 AND t+3
// back-to-back per row (offset 0 / 512 on one base) makes each page visit
// 1KB sequential, halving activates. Compute/LDS identical to R18:
// bf16 A-store + XOR swizzle, 2m x 4n waves, X 3-buffer DMA, 1 barrier/phase.
// vmcnt audit (issue order [p0q0p1q1p2q2p3q3, XD]): odd TOP=12, store-p=5,
// even TOP=4 (also covers q), prologue store=9; drain only at t=127.

#define N_NODES 16384
#define DIM     128
#define NTYPES  8
#define BM      64
#define BK      128
#define NT_K    (N_NODES / BK)   // 128 phases

typedef float  f32x4  __attribute__((ext_vector_type(4)));
typedef __bf16 bf16x4 __attribute__((ext_vector_type(4)));
typedef __bf16 bf16x8 __attribute__((ext_vector_type(8)));

__device__ __attribute__((aligned(16))) unsigned short g_xT[DIM * N_NODES];      // [d][n], 4 MiB bf16
__device__ __attribute__((aligned(16))) unsigned short g_Wb[NTYPES * DIM * DIM]; // [t][o][d], 256 KiB

__device__ __forceinline__ unsigned int f2b(float f) {
    unsigned int u = __float_as_uint(f);
    u += 0x7FFFu + ((u >> 16) & 1u);   // round-to-nearest-even
    return u >> 16;
}
#define BF_LO(u) __uint_as_float((unsigned int)(u) << 16)
#define BF_HI(u) __uint_as_float((unsigned int)(u) & 0xFFFF0000u)

__device__ __forceinline__ bf16x4 cvt4(const f32x4 v) {
    bf16x4 r;
    r[0] = (__bf16)v[0]; r[1] = (__bf16)v[1]; r[2] = (__bf16)v[2]; r[3] = (__bf16)v[3];
    return r;
}

// ---------------- fused prep kernel ----------------

__global__ void prep_all(const float* __restrict__ x, const float* __restrict__ w) {
    const int tid = threadIdx.x;
    if (blockIdx.x < 64) {
        int n = blockIdx.x * 256 + tid;
        const float* row = x + (size_t)n * DIM;
#pragma unroll
        for (int d0 = 0; d0 < DIM; d0 += 4) {
            float4 v = *(const float4*)(row + d0);
            g_xT[(d0 + 0) * N_NODES + n] = (unsigned short)f2b(v.x);
            g_xT[(d0 + 1) * N_NODES + n] = (unsigned short)f2b(v.y);
            g_xT[(d0 + 2) * N_NODES + n] = (unsigned short)f2b(v.z);
            g_xT[(d0 + 3) * N_NODES + n] = (unsigned short)f2b(v.w);
        }
    } else {
        int base = ((blockIdx.x - 64) * 256 + tid) * 16;
#pragma unroll
        for (int j = 0; j < 4; ++j) {
            float4 v = *(const float4*)(w + base + j * 4);
            ushort4 o;
            o.x = (unsigned short)f2b(v.x); o.y = (unsigned short)f2b(v.y);
            o.z = (unsigned short)f2b(v.z); o.w = (unsigned short)f2b(v.w);
            *(ushort4*)(g_Wb + base + j * 4) = o;
        }
    }
}

// ---------------- main fused kernel ----------------

#define AB_BYTES 16384   // A tile bf16: 64 rows x 256B
#define XB_BYTES 32768   // X tile bf16: 128 d-rows x 256B

#define GLOAD16(g, l) __builtin_amdgcn_global_load_lds(                         \
    (const __attribute__((address_space(1))) unsigned int*)(g),                 \
    (__attribute__((address_space(3))) unsigned int*)(l), 16, 0, 0)

// pinned A load with immediate byte offset
#define ALOADI(reg, ptr, off) \
    asm volatile("global_load_dwordx4 %0, %1, off offset:" #off : "=v"(reg) : "v"(ptr))

// paired issue: tiles (t+2)->p at offset 0, (t+3)->q at offset 512, per-row
// back-to-back so the controller sees 1KB sequential per row.
#define ISSUE_AL2() do {                          \
    ALOADI(p0, pA0, 0); ALOADI(q0, pA0, 512);     \
    ALOADI(p1, pA1, 0); ALOADI(q1, pA1, 512);     \
    ALOADI(p2, pA2, 0); ALOADI(q2, pA2, 512);     \
    ALOADI(p3, pA3, 0); ALOADI(q3, pA3, 512);     \
    pA0 += 256; pA1 += 256; pA2 += 256; pA3 += 256; \
} while (0)

#define ISSUE_XD(Xb) do {                        \
    GLOAD16(gX0, (Xb) + 0 * 8192 + wq);          \
    GLOAD16(gX1, (Xb) + 1 * 8192 + wq);          \
    GLOAD16(gX2, (Xb) + 2 * 8192 + wq);          \
    GLOAD16(gX3, (Xb) + 3 * 8192 + wq);          \
    gX0 += BK; gX1 += BK; gX2 += BK; gX3 += BK;  \
} while (0)

// cvt + swizzled bf16 store of one staged tile (4 x 8B writes/thread)
#define STOREA(As, R0, R1, R2, R3) do {          \
    *(bf16x4*)((As) + aw0) = cvt4(R0);           \
    *(bf16x4*)((As) + aw1) = cvt4(R1);           \
    *(bf16x4*)((As) + aw2) = cvt4(R2);           \
    *(bf16x4*)((As) + aw3) = cvt4(R3);           \
} while (0)

// one k-substep (k=32): 2 A frags x 2 X frags -> 4 MFMA (A and X share `off`)
#define KS(Ab, Xb, off) do {                                                    \
    bf16x8 a0_ = *(const bf16x8*)((Ab) + arA0 + (off));                         \
    bf16x8 a1_ = *(const bf16x8*)((Ab) + arA1 + (off));                         \
    bf16x8 b0_ = *(const bf16x8*)((Xb) + xB0 + (off));                          \
    bf16x8 b1_ = *(const bf16x8*)((Xb) + xB1 + (off));                          \
    acc00 = __builtin_amdgcn_mfma_f32_16x16x32_bf16(a0_, b0_, acc00, 0, 0, 0);  \
    acc01 = __builtin_amdgcn_mfma_f32_16x16x32_bf16(a0_, b1_, acc01, 0, 0, 0);  \
    acc10 = __builtin_amdgcn_mfma_f32_16x16x32_bf16(a1_, b0_, acc10, 0, 0, 0);  \
    acc11 = __builtin_amdgcn_mfma_f32_16x16x32_bf16(a1_, b1_, acc11, 0, 0, 0);  \
} while (0)

#define COMPUTE(Ab, Xb) do {      \
    KS(Ab, Xb, off0);             \
    KS(Ab, Xb, off1);             \
    KS(Ab, Xb, off2);             \
    KS(Ab, Xb, off3);             \
} while (0)

#define WAITV(N) do {                                        \
    asm volatile("s_waitcnt vmcnt(" #N ")" ::: "memory");    \
    __builtin_amdgcn_sched_barrier(0);                       \
} while (0)

// phase top: X(t) done (VM younger ops stay in flight), A-stores visible
#define TOP(VM) do {                                                            \
    asm volatile("s_waitcnt vmcnt(" #VM ") lgkmcnt(0)\n\ts_barrier" ::: "memory"); \
    __builtin_amdgcn_sched_barrier(0);                                          \
} while (0)

// odd phase t: compute A(t)@Ab1; wait p (tile t+1... p=even tile t+1);
// store p -> Ab0; issue XD(t+2).
#define PH_ODD(Xc, Xi) do {                      \
    TOP(12);                                     \
    COMPUTE(Ab1, Xc);                            \
    WAITV(5);                                    \
    STOREA(Ab0, p0, p1, p2, p3);                 \
    ISSUE_XD(Xi);                                \
} while (0)

// even phase t: compute A(t)@Ab0; store q (odd tile t+1) -> Ab1 (q already
// complete at vmcnt(4)); paired-issue AL(t+2),AL(t+3); issue XD(t+2).
#define PH_EVEN(Xc, Xi) do {                     \
    TOP(4);                                      \
    COMPUTE(Ab0, Xc);                            \
    STOREA(Ab1, q0, q1, q2, q3);                 \
    ISSUE_AL2();                                 \
    ISSUE_XD(Xi);                                \
} while (0)

__global__ __launch_bounds__(512, 1) void gconv_main(
    const float* __restrict__ adj,
    const int* __restrict__ types,
    float* __restrict__ out)
{
    __shared__ __align__(16) unsigned char lds[3 * XB_BYTES + 2 * AB_BYTES]; // 131072 B
    unsigned char* X0 = lds;
    unsigned char* X1 = lds + XB_BYTES;
    unsigned char* X2 = lds + 2 * XB_BYTES;
    unsigned char* Ab0 = lds + 3 * XB_BYTES;
    unsigned char* Ab1 = Ab0 + AB_BYTES;

    const int tid  = threadIdx.x;
    const int w    = tid >> 6;          // 0..7
    const int l    = tid & 63;
    const int m0   = blockIdx.x * BM;

    const int mrow = (w & 1) * 32;      // wave tile: 32 rows (2 m-tiles)
    const int ncol = (w >> 1) * 32;     //          x 32 cols (2 n-tiles)
    const int h    = l >> 4;            // k-quarter within ksub

    f32x4 acc00 = {}, acc01 = {}, acc10 = {}, acc11 = {};

    // ---- A staging: instr j = rows w*8 + j*2 + (l>>5), bytes (l&31)*16 ----
    const int rj0 = w * 8 + 0 + (l >> 5);
    const int rj1 = w * 8 + 2 + (l >> 5);
    const int rj2 = w * 8 + 4 + (l >> 5);
    const int rj3 = w * 8 + 6 + (l >> 5);
    const float* pA0 = adj + (size_t)(m0 + rj0) * N_NODES + (l & 31) * 4;
    const float* pA1 = adj + (size_t)(m0 + rj1) * N_NODES + (l & 31) * 4;
    const float* pA2 = adj + (size_t)(m0 + rj2) * N_NODES + (l & 31) * 4;
    const float* pA3 = adj + (size_t)(m0 + rj3) * N_NODES + (l & 31) * 4;
    // bf16 store addr: granule g=l&31 -> chunk g>>1 (XOR row&7), half g&1
    const int g_  = l & 31;
    const int aw0 = rj0 * 256 + ((((g_ >> 1) ^ (rj0 & 7))) << 4) + ((g_ & 1) << 3);
    const int aw1 = rj1 * 256 + ((((g_ >> 1) ^ (rj1 & 7))) << 4) + ((g_ & 1) << 3);
    const int aw2 = rj2 * 256 + ((((g_ >> 1) ^ (rj2 & 7))) << 4) + ((g_ & 1) << 3);
    const int aw3 = rj3 * 256 + ((((g_ >> 1) ^ (rj3 & 7))) << 4) + ((g_ & 1) << 3);

    // ---- X DMA (R13/R18-verified): call j: d-row = j*32 + 4w + (l>>4) ----
    const int xdw = 4 * w + (l >> 4);
    const unsigned short* gX0 = g_xT + (size_t)( 0 + xdw) * N_NODES + (((l & 15) ^ (xdw & 7)) << 3);
    const unsigned short* gX1 = g_xT + (size_t)(32 + xdw) * N_NODES + (((l & 15) ^ (xdw & 7)) << 3);
    const unsigned short* gX2 = g_xT + (size_t)(64 + xdw) * N_NODES + (((l & 15) ^ (xdw & 7)) << 3);
    const unsigned short* gX3 = g_xT + (size_t)(96 + xdw) * N_NODES + (((l & 15) ^ (xdw & 7)) << 3);
    const int wq = w << 10;

    // ---- compute-side bases/offsets (A and X share the XOR-chunk formula) ----
    const int arA0 = (mrow +  0 + (l & 15)) * 256;
    const int arA1 = (mrow + 16 + (l & 15)) * 256;
    const int xB0  = (ncol +  0 + (l & 15)) * 256;
    const int xB1  = (ncol + 16 + (l & 15)) * 256;
    const int off0 = (( 0 + h) ^ (l & 7)) << 4;
    const int off1 = (( 4 + h) ^ (l & 7)) << 4;
    const int off2 = (( 8 + h) ^ (l & 7)) << 4;
    const int off3 = ((12 + h) ^ (l & 7)) << 4;

    // ---- A register parities (p = even tiles, q = odd tiles) ----
    f32x4 p0, p1, p2, p3, q0, q1, q2, q3;

    // ---- prologue: AL(0,1) paired, XD(0), XD(1); store A(0) ----
    ISSUE_AL2();                  // tiles 0(p), 1(q)   [8 ops]
    ISSUE_XD(X0);                 // [4]
    ISSUE_XD(X1);                 // [4]
    WAITV(9);                     // p3 done (q3 + XD0 + XD1 = 9 younger)
    STOREA(Ab0, p0, p1, p2, p3);
    // phase 0 (even): TOP(4) -> XD(0) done (XD(1)=4 younger)
    TOP(4);
    COMPUTE(Ab0, X0);
    STOREA(Ab1, q0, q1, q2, q3);  // q complete (older than XD(0))
    ISSUE_AL2();                  // tiles 2,3
    ISSUE_XD(X2);                 // XD(2)

    // ---- phases 1..120: 20 x 6 ----
    for (int i = 0; i < 20; ++i) {
        PH_ODD (X1, X0);          // t=6i+1: consume X1, XD(t+2)->X0
        PH_EVEN(X2, X1);          // t=6i+2
        PH_ODD (X0, X2);          // t=6i+3
        PH_EVEN(X1, X0);          // t=6i+4
        PH_ODD (X2, X1);          // t=6i+5
        PH_EVEN(X0, X2);          // t=6i+6
    }
    // ---- phases 121..125 (steady), 126 (no-issue even), 127 (tail) ----
    PH_ODD (X1, X0);              // t=121
    PH_EVEN(X2, X1);              // t=122: AL(124,125), XD(124)
    PH_ODD (X0, X2);              // t=123: XD(125)
    PH_EVEN(X1, X0);              // t=124: AL(126,127), XD(126)
    PH_ODD (X2, X1);              // t=125: XD(127)
    TOP(4);                       // t=126: XD(126) done (XD(127)=4 younger)
    COMPUTE(Ab0, X0);
    STOREA(Ab1, q0, q1, q2, q3);  // A(127)
    TOP(0);                       // t=127: full drain
    COMPUTE(Ab1, X1);
    __syncthreads();              // before reusing LDS as agg

    // ---- epilogue: acc -> LDS agg (f32), then per-row W[type] dots ----
    float* agg = (float*)lds;   // [64][132] = 33792 B
#pragma unroll
    for (int r = 0; r < 4; ++r) {
        const int r0 = (mrow +  0 + h * 4 + r) * 132 + ncol + (l & 15);
        const int r1 = (mrow + 16 + h * 4 + r) * 132 + ncol + (l & 15);
        agg[r0 +  0] = acc00[r];
        agg[r0 + 16] = acc01[r];
        agg[r1 +  0] = acc10[r];
        agg[r1 + 16] = acc11[r];
    }
    __syncthreads();

    const int rbase = w * 8;   // 8 rows per wave
    for (int rr = 0; rr < 8; ++rr) {
        const int rw = rbase + rr;
        const int nn = m0 + rw;
        const int ty = types[nn];                      // wave-uniform
        const unsigned short* Wt = g_Wb + ty * (DIM * DIM);
        const int o0 = l * 2;
        const float* aggRow = agg + rw * 132;
        float s0 = 0.f, s1 = 0.f;
#pragma unroll
        for (int d0 = 0; d0 < DIM; d0 += 8) {
            float4 ga = *(const float4*)(aggRow + d0);
            float4 gb = *(const float4*)(aggRow + d0 + 4);
            uint4 wa = *(const uint4*)(Wt + o0 * DIM + d0);
            uint4 wb = *(const uint4*)(Wt + (o0 + 1) * DIM + d0);
            s0 += ga.x * BF_LO(wa.x) + ga.y * BF_HI(wa.x) + ga.z * BF_LO(wa.y) + ga.w * BF_HI(wa.y);
            s0 += gb.x * BF_LO(wa.z) + gb.y * BF_HI(wa.z) + gb.z * BF_LO(wa.w) + gb.w * BF_HI(wa.w);
            s1 += ga.x * BF_LO(wb.x) + ga.y * BF_HI(wb.x) + ga.z * BF_LO(wb.y) + ga.w * BF_HI(wb.y);
            s1 += gb.x * BF_LO(wb.z) + gb.y * BF_HI(wb.z) + gb.z * BF_LO(wb.w) + gb.w * BF_HI(wb.w);
        }
        float2 res; res.x = s0; res.y = s1;
        *(float2*)(out + (size_t)nn * DIM + o0) = res;
    }
}

// ---------------- launch ----------------

extern "C" void kernel_launch(void* const* d_in, const int* in_sizes, int n_in,
                              void* d_out, int out_size, void* d_ws, size_t ws_size,
                              hipStream_t stream) {
    const float* x     = (const float*)d_in[0];
    const int*   types = (const int*)d_in[1];
    const float* adj   = (const float*)d_in[2];
    const float* wt    = (const float*)d_in[3];
    float* out = (float*)d_out;

    hipLaunchKernelGGL(prep_all, dim3(96), dim3(256), 0, stream, x, wt);
    hipLaunchKernelGGL(gconv_main, dim3(N_NODES / BM), dim3(512), 0, stream, adj, types, out);
}

// Round 21
// 285.815 us; speedup vs baseline: 2.4665x; 1.0128x over previous
//
#include <hip/hip_runtime.h>
#include <stdint.h>

// GraphConvLayer: out[n,:] = W[type[n]] @ (A @ x)[n,:]
// N=16384, D=128, T=8.  A is 1 GiB f32 read exactly once -> HBM floor ~163us.
// Round 21 = Round 19 (best, 289us) + 4-deep A pairing, CLOBBER-FREE.
// R20's crash: ISSUE_AL4 at phase A0 rewrote parities r,s before their
// stores. Fix: AL4 issues at phase A2 AFTER the s-store, when all four
// parities are dead (q@A0, r@A1, s@A2, p@prev-A3). Each row-visit is 4
// back-to-back 16B loads (offset 0/512/1024/1536) = 2KB sequential per
// DRAM page (R13 512B:+41us, R19 1KB:+13us - the only live lever).
// vmcnt ledger (younger-op counting, in-order retire), steady state:
//   A0: TOP(4)  store q (complete via TOP)        issue XD
//   A1: TOP(4)  store r                            issue XD
//   A2: TOP(4)  store s   -> ISSUE_AL4 (16 ops)    issue XD
//   A3: TOP(20) WAITV(7) -> store p (new group)    issue XD
// prologue WAITV(8); tail TOP 4/4/4/0. X path/swizzle identical to R19.

#define N_NODES 16384
#define DIM     128
#define NTYPES  8
#define BM      64
#define BK      128
#define NT_K    (N_NODES / BK)   // 128 phases

typedef float  f32x4  __attribute__((ext_vector_type(4)));
typedef __bf16 bf16x4 __attribute__((ext_vector_type(4)));
typedef __bf16 bf16x8 __attribute__((ext_vector_type(8)));

__device__ __attribute__((aligned(16))) unsigned short g_xT[DIM * N_NODES];      // [d][n], 4 MiB bf16
__device__ __attribute__((aligned(16))) unsigned short g_Wb[NTYPES * DIM * DIM]; // [t][o][d], 256 KiB

__device__ __forceinline__ unsigned int f2b(float f) {
    unsigned int u = __float_as_uint(f);
    u += 0x7FFFu + ((u >> 16) & 1u);   // round-to-nearest-even
    return u >> 16;
}
#define BF_LO(u) __uint_as_float((unsigned int)(u) << 16)
#define BF_HI(u) __uint_as_float((unsigned int)(u) & 0xFFFF0000u)

__device__ __forceinline__ bf16x4 cvt4(const f32x4 v) {
    bf16x4 r;
    r[0] = (__bf16)v[0]; r[1] = (__bf16)v[1]; r[2] = (__bf16)v[2]; r[3] = (__bf16)v[3];
    return r;
}

// ---------------- fused prep kernel ----------------

__global__ void prep_all(const float* __restrict__ x, const float* __restrict__ w) {
    const int tid = threadIdx.x;
    if (blockIdx.x < 64) {
        int n = blockIdx.x * 256 + tid;
        const float* row = x + (size_t)n * DIM;
#pragma unroll
        for (int d0 = 0; d0 < DIM; d0 += 4) {
            float4 v = *(const float4*)(row + d0);
            g_xT[(d0 + 0) * N_NODES + n] = (unsigned short)f2b(v.x);
            g_xT[(d0 + 1) * N_NODES + n] = (unsigned short)f2b(v.y);
            g_xT[(d0 + 2) * N_NODES + n] = (unsigned short)f2b(v.z);
            g_xT[(d0 + 3) * N_NODES + n] = (unsigned short)f2b(v.w);
        }
    } else {
        int base = ((blockIdx.x - 64) * 256 + tid) * 16;
#pragma unroll
        for (int j = 0; j < 4; ++j) {
            float4 v = *(const float4*)(w + base + j * 4);
            ushort4 o;
            o.x = (unsigned short)f2b(v.x); o.y = (unsigned short)f2b(v.y);
            o.z = (unsigned short)f2b(v.z); o.w = (unsigned short)f2b(v.w);
            *(ushort4*)(g_Wb + base + j * 4) = o;
        }
    }
}

// ---------------- main fused kernel ----------------

#define AB_BYTES 16384   // A tile bf16: 64 rows x 256B
#define XB_BYTES 32768   // X tile bf16: 128 d-rows x 256B

#define GLOAD16(g, l) __builtin_amdgcn_global_load_lds(                         \
    (const __attribute__((address_space(1))) unsigned int*)(g),                 \
    (__attribute__((address_space(3))) unsigned int*)(l), 16, 0, 0)

#define ALOADI(reg, ptr, off) \
    asm volatile("global_load_dwordx4 %0, %1, off offset:" #off : "=v"(reg) : "v"(ptr))

// 4-deep paired issue: tiles t..t+3 -> p/q/r/s, 4 back-to-back loads per row
// = 2KB sequential per page visit. Issued ONLY at A2 phases (all parities dead).
#define ISSUE_AL4() do {                                                   \
    ALOADI(p0, pA0, 0); ALOADI(q0, pA0, 512); ALOADI(r0, pA0, 1024); ALOADI(s0, pA0, 1536); \
    ALOADI(p1, pA1, 0); ALOADI(q1, pA1, 512); ALOADI(r1, pA1, 1024); ALOADI(s1, pA1, 1536); \
    ALOADI(p2, pA2, 0); ALOADI(q2, pA2, 512); ALOADI(r2, pA2, 1024); ALOADI(s2, pA2, 1536); \
    ALOADI(p3, pA3, 0); ALOADI(q3, pA3, 512); ALOADI(r3, pA3, 1024); ALOADI(s3, pA3, 1536); \
    pA0 += 512; pA1 += 512; pA2 += 512; pA3 += 512;                        \
} while (0)

#define ISSUE_XD(Xb) do {                        \
    GLOAD16(gX0, (Xb) + 0 * 8192 + wq);          \
    GLOAD16(gX1, (Xb) + 1 * 8192 + wq);          \
    GLOAD16(gX2, (Xb) + 2 * 8192 + wq);          \
    GLOAD16(gX3, (Xb) + 3 * 8192 + wq);          \
    gX0 += BK; gX1 += BK; gX2 += BK; gX3 += BK;  \
} while (0)

#define STOREA(As, R0, R1, R2, R3) do {          \
    *(bf16x4*)((As) + aw0) = cvt4(R0);           \
    *(bf16x4*)((As) + aw1) = cvt4(R1);           \
    *(bf16x4*)((As) + aw2) = cvt4(R2);           \
    *(bf16x4*)((As) + aw3) = cvt4(R3);           \
} while (0)

#define KS(Ab, Xb, off) do {                                                    \
    bf16x8 a0_ = *(const bf16x8*)((Ab) + arA0 + (off));                         \
    bf16x8 a1_ = *(const bf16x8*)((Ab) + arA1 + (off));                         \
    bf16x8 b0_ = *(const bf16x8*)((Xb) + xB0 + (off));                          \
    bf16x8 b1_ = *(const bf16x8*)((Xb) + xB1 + (off));                          \
    acc00 = __builtin_amdgcn_mfma_f32_16x16x32_bf16(a0_, b0_, acc00, 0, 0, 0);  \
    acc01 = __builtin_amdgcn_mfma_f32_16x16x32_bf16(a0_, b1_, acc01, 0, 0, 0);  \
    acc10 = __builtin_amdgcn_mfma_f32_16x16x32_bf16(a1_, b0_, acc10, 0, 0, 0);  \
    acc11 = __builtin_amdgcn_mfma_f32_16x16x32_bf16(a1_, b1_, acc11, 0, 0, 0);  \
} while (0)

#define COMPUTE(Ab, Xb) do {      \
    KS(Ab, Xb, off0);             \
    KS(Ab, Xb, off1);             \
    KS(Ab, Xb, off2);             \
    KS(Ab, Xb, off3);             \
} while (0)

#define WAITV(N) do {                                        \
    asm volatile("s_waitcnt vmcnt(" #N ")" ::: "memory");    \
    __builtin_amdgcn_sched_barrier(0);                       \
} while (0)

#define TOP(VM) do {                                                            \
    asm volatile("s_waitcnt vmcnt(" #VM ") lgkmcnt(0)\n\ts_barrier" ::: "memory"); \
    __builtin_amdgcn_sched_barrier(0);                                          \
} while (0)

// Phase macros (t mod 4). Ledger (younger-op counting, in-order retire):
// A0: before TOP: [q3,r3,s3, XD(t), XD(t+1)] -> TOP(4) completes XD(t) AND
//     the old AL4 stragglers -> q,r,s valid for A0/A1/A2 stores, no waits.
// A2: issues AL4 after the s-store (parities all dead -> no clobber).
// A3: before TOP: [XD(t), AL4(16), XD(t+1)] = 24 -> TOP(20); p3's youngers
//     = q3,r3,s3 + XD(t+1) = 7 -> WAITV(7) before the p-store.
#define PH_A0(Xc, Xi) do { TOP(4);  COMPUTE(Ab0, Xc); STOREA(Ab1, q0,q1,q2,q3); ISSUE_XD(Xi); } while (0)
#define PH_A1(Xc, Xi) do { TOP(4);  COMPUTE(Ab1, Xc); STOREA(Ab0, r0,r1,r2,r3); ISSUE_XD(Xi); } while (0)
#define PH_A2(Xc, Xi) do { TOP(4);  COMPUTE(Ab0, Xc); STOREA(Ab1, s0,s1,s2,s3); ISSUE_AL4(); ISSUE_XD(Xi); } while (0)
#define PH_A3(Xc, Xi) do { TOP(20); COMPUTE(Ab1, Xc); WAITV(7); STOREA(Ab0, p0,p1,p2,p3); ISSUE_XD(Xi); } while (0)

__global__ __launch_bounds__(512, 1) void gconv_main(
    const float* __restrict__ adj,
    const int* __restrict__ types,
    float* __restrict__ out)
{
    __shared__ __align__(16) unsigned char lds[3 * XB_BYTES + 2 * AB_BYTES]; // 131072 B
    unsigned char* X0 = lds;
    unsigned char* X1 = lds + XB_BYTES;
    unsigned char* X2 = lds + 2 * XB_BYTES;
    unsigned char* Ab0 = lds + 3 * XB_BYTES;
    unsigned char* Ab1 = Ab0 + AB_BYTES;

    const int tid  = threadIdx.x;
    const int w    = tid >> 6;          // 0..7
    const int l    = tid & 63;
    const int m0   = blockIdx.x * BM;

    const int mrow = (w & 1) * 32;      // wave tile: 32 rows (2 m-tiles)
    const int ncol = (w >> 1) * 32;     //          x 32 cols (2 n-tiles)
    const int h    = l >> 4;            // k-quarter within ksub

    f32x4 acc00 = {}, acc01 = {}, acc10 = {}, acc11 = {};

    // ---- A staging: instr row j = w*8 + j*2 + (l>>5), bytes (l&31)*16 ----
    const int rj0 = w * 8 + 0 + (l >> 5);
    const int rj1 = w * 8 + 2 + (l >> 5);
    const int rj2 = w * 8 + 4 + (l >> 5);
    const int rj3 = w * 8 + 6 + (l >> 5);
    const float* pA0 = adj + (size_t)(m0 + rj0) * N_NODES + (l & 31) * 4;
    const float* pA1 = adj + (size_t)(m0 + rj1) * N_NODES + (l & 31) * 4;
    const float* pA2 = adj + (size_t)(m0 + rj2) * N_NODES + (l & 31) * 4;
    const float* pA3 = adj + (size_t)(m0 + rj3) * N_NODES + (l & 31) * 4;
    // bf16 store addr: granule g=l&31 -> chunk g>>1 (XOR row&7), half g&1
    const int g_  = l & 31;
    const int aw0 = rj0 * 256 + ((((g_ >> 1) ^ (rj0 & 7))) << 4) + ((g_ & 1) << 3);
    const int aw1 = rj1 * 256 + ((((g_ >> 1) ^ (rj1 & 7))) << 4) + ((g_ & 1) << 3);
    const int aw2 = rj2 * 256 + ((((g_ >> 1) ^ (rj2 & 7))) << 4) + ((g_ & 1) << 3);
    const int aw3 = rj3 * 256 + ((((g_ >> 1) ^ (rj3 & 7))) << 4) + ((g_ & 1) << 3);

    // ---- X DMA (R13/R18/R19-verified): call j: d-row = j*32 + 4w + (l>>4) ----
    const int xdw = 4 * w + (l >> 4);
    const unsigned short* gX0 = g_xT + (size_t)( 0 + xdw) * N_NODES + (((l & 15) ^ (xdw & 7)) << 3);
    const unsigned short* gX1 = g_xT + (size_t)(32 + xdw) * N_NODES + (((l & 15) ^ (xdw & 7)) << 3);
    const unsigned short* gX2 = g_xT + (size_t)(64 + xdw) * N_NODES + (((l & 15) ^ (xdw & 7)) << 3);
    const unsigned short* gX3 = g_xT + (size_t)(96 + xdw) * N_NODES + (((l & 15) ^ (xdw & 7)) << 3);
    const int wq = w << 10;

    // ---- compute-side bases/offsets ----
    const int arA0 = (mrow +  0 + (l & 15)) * 256;
    const int arA1 = (mrow + 16 + (l & 15)) * 256;
    const int xB0  = (ncol +  0 + (l & 15)) * 256;
    const int xB1  = (ncol + 16 + (l & 15)) * 256;
    const int off0 = (( 0 + h) ^ (l & 7)) << 4;
    const int off1 = (( 4 + h) ^ (l & 7)) << 4;
    const int off2 = (( 8 + h) ^ (l & 7)) << 4;
    const int off3 = ((12 + h) ^ (l & 7)) << 4;

    // ---- A register parities: tiles 4j/4j+1/4j+2/4j+3 -> p/q/r/s ----
    f32x4 p0, p1, p2, p3, q0, q1, q2, q3,
          r0, r1, r2, r3, s0, s1, s2, s3;

    // ---- prologue: AL4(tiles 0-3) [16], XD(0) [4], XD(1) [4]; store A(0) ----
    ISSUE_AL4();
    ISSUE_XD(X0);
    ISSUE_XD(X1);
    WAITV(8);                     // AL4 done (XD0+XD1 = 8 younger)
    STOREA(Ab0, p0, p1, p2, p3);

    // ---- t = 0..119: 10 x period-12 (A period 4, X period 3) ----
    for (int i = 0; i < 10; ++i) {
        PH_A0(X0, X2); PH_A1(X1, X0); PH_A2(X2, X1); PH_A3(X0, X2);
        PH_A0(X1, X0); PH_A1(X2, X1); PH_A2(X0, X2); PH_A3(X1, X0);
        PH_A0(X2, X1); PH_A1(X0, X2); PH_A2(X1, X0); PH_A3(X2, X1);
    }
    // ---- t = 120..123 (AL4@122 loads tiles 124-127; p(124) stored @123) ----
    PH_A0(X0, X2); PH_A1(X1, X0); PH_A2(X2, X1); PH_A3(X0, X2);
    // ---- tail t = 124..127 (no more AL4) ----
    TOP(4);                       // t=124: XD(124) done (XD(125)=4 younger; forces q3,r3,s3)
    COMPUTE(Ab0, X1);
    STOREA(Ab1, q0, q1, q2, q3);  // A(125)
    ISSUE_XD(X0);                 // XD(126)
    TOP(4);                       // t=125: XD(125) done (XD(126)=4)
    COMPUTE(Ab1, X2);
    STOREA(Ab0, r0, r1, r2, r3);  // A(126)
    ISSUE_XD(X1);                 // XD(127)
    TOP(4);                       // t=126: XD(126) done (XD(127)=4)
    COMPUTE(Ab0, X0);
    STOREA(Ab1, s0, s1, s2, s3);  // A(127)
    TOP(0);                       // t=127: full drain
    COMPUTE(Ab1, X1);
    __syncthreads();              // before reusing LDS as agg

    // ---- epilogue: acc -> LDS agg (f32), then per-row W[type] dots ----
    float* agg = (float*)lds;   // [64][132] = 33792 B
#pragma unroll
    for (int rr = 0; rr < 4; ++rr) {
        const int e0 = (mrow +  0 + h * 4 + rr) * 132 + ncol + (l & 15);
        const int e1 = (mrow + 16 + h * 4 + rr) * 132 + ncol + (l & 15);
        agg[e0 +  0] = acc00[rr];
        agg[e0 + 16] = acc01[rr];
        agg[e1 +  0] = acc10[rr];
        agg[e1 + 16] = acc11[rr];
    }
    __syncthreads();

    const int rbase = w * 8;   // 8 rows per wave
    for (int rr = 0; rr < 8; ++rr) {
        const int rw = rbase + rr;
        const int nn = m0 + rw;
        const int ty = types[nn];                      // wave-uniform
        const unsigned short* Wt = g_Wb + ty * (DIM * DIM);
        const int o0 = l * 2;
        const float* aggRow = agg + rw * 132;
        float t0 = 0.f, t1 = 0.f;
#pragma unroll
        for (int d0 = 0; d0 < DIM; d0 += 8) {
            float4 ga = *(const float4*)(aggRow + d0);
            float4 gb = *(const float4*)(aggRow + d0 + 4);
            uint4 wa = *(const uint4*)(Wt + o0 * DIM + d0);
            uint4 wb = *(const uint4*)(Wt + (o0 + 1) * DIM + d0);
            t0 += ga.x * BF_LO(wa.x) + ga.y * BF_HI(wa.x) + ga.z * BF_LO(wa.y) + ga.w * BF_HI(wa.y);
            t0 += gb.x * BF_LO(wa.z) + gb.y * BF_HI(wa.z) + gb.z * BF_LO(wa.w) + gb.w * BF_HI(wa.w);
            t1 += ga.x * BF_LO(wb.x) + ga.y * BF_HI(wb.x) + ga.z * BF_LO(wb.y) + ga.w * BF_HI(wb.y);
            t1 += gb.x * BF_LO(wb.z) + gb.y * BF_HI(wb.z) + gb.z * BF_LO(wb.w) + gb.w * BF_HI(wb.w);
        }
        float2 res; res.x = t0; res.y = t1;
        *(float2*)(out + (size_t)nn * DIM + o0) = res;
    }
}

// ---------------- launch ----------------

extern "C" void kernel_launch(void* const* d_in, const int* in_sizes, int n_in,
                              void* d_out, int out_size, void* d_ws, size_t ws_size,
                              hipStream_t stream) {
    const float* x     = (const float*)d_in[0];
    const int*   types = (const int*)d_in[1];
    const float* adj   = (const float*)d_in[2];
    const float* wt    = (const float*)d_in[3];
    float* out = (float*)d_out;

    hipLaunchKernelGGL(prep_all, dim3(96), dim3(256), 0, stream, x, wt);
    hipLaunchKernelGGL(gconv_main, dim3(N_NODES / BM), dim3(512), 0, stream, adj, types, out);
}